// Round 7
// baseline (70.400 us; speedup 1.0000x reference)
//
#include <hip/hip_runtime.h>
#include <math.h>

#define Bsz 32
#define Cc  16
#define Hh  64
#define Ww  64
#define HO  62
#define WO  62
#define OD  64
#define ND  144
#define KC  18            // K-steps of 64 (8 slots x 8 feats)
#define FEAT_U4 (4096 + 16)   // 16c x 4r x 64w uint4 + overreach pad (65,792 B)

using short8 = __attribute__((ext_vector_type(8))) short;
using f32x4  = __attribute__((ext_vector_type(4))) float;
using f32x16 = __attribute__((ext_vector_type(16))) float;
typedef unsigned int u32;
typedef unsigned short ushort;

__device__ __forceinline__ ushort f2bf(float f) {
    union { float f; unsigned u; } v; v.f = f;
    unsigned r = v.u + 0x7fff + ((v.u >> 16) & 1);
    return (ushort)(r >> 16);
}
__device__ __forceinline__ float bf2f(ushort h) {
    union { unsigned u; float f; } v; v.u = ((unsigned)h) << 16; return v.f;
}

__device__ __forceinline__ uint4 feat_pack(float xv) {
    float xi = (xv + 3.0f) * 1.5f;
    float fi = floorf(xi);
    int   ii = (int)fi;
    float u  = xi - fi;
    float u2 = u * u, u3 = u2 * u;
    float P0 = u3 * (1.0f / 6.0f);
    float P1 = (1.0f + 3.0f * u + 3.0f * u2 - 3.0f * u3) * (1.0f / 6.0f);
    float P2 = (4.0f - 6.0f * u2 + 3.0f * u3) * (1.0f / 6.0f);
    float om = 1.0f - u;
    float P3 = om * om * om * (1.0f / 6.0f);
    bool ok = (ii >= 0) && (ii <= 8);
    float bas[6];
    #pragma unroll
    for (int n = 0; n < 6; ++n) {
        int t = ii - n;
        float v = (t == 0) ? P0 : (t == 1) ? P1 : (t == 2) ? P2 : (t == 3) ? P3 : 0.0f;
        bas[n] = ok ? v : 0.0f;
    }
    float s = xv / (1.0f + __expf(-xv));
    ushort sh = f2bf(s);
    ushort sl = f2bf(s - bf2f(sh));
    uint4 pk;
    pk.x = (unsigned)f2bf(bas[0]) | ((unsigned)f2bf(bas[1]) << 16);
    pk.y = (unsigned)f2bf(bas[2]) | ((unsigned)f2bf(bas[3]) << 16);
    pk.z = (unsigned)f2bf(bas[4]) | ((unsigned)f2bf(bas[5]) << 16);
    pk.w = (unsigned)sh | ((unsigned)sl << 16);
    return pk;
}

// ---- B image, c-pair K-permutation: slot(kc,sl) -> d = (2a+par)*9 + rem,
//      where p = kc*4 + (sl>>1) = a*9 + rem, par = sl&1 ----
__global__ __launch_bounds__(256) void kan_prep4(const float* __restrict__ coef,
                                                 const float* __restrict__ sbase,
                                                 const float* __restrict__ ssp,
                                                 ushort* __restrict__ wpb) {
    int g = blockIdx.x * 256 + threadIdx.x;        // (slot, n)
    if (g >= KC * 8 * 64) return;
    int n = g & 63, slot = g >> 6;                 // slot 0..143
    int kc = slot >> 3, sl = slot & 7, kk = sl >> 1, par = sl & 1;
    int p = kc * 4 + kk;                           // 0..71
    int a = p / 9, rem = p - a * 9;
    int d = (2 * a + par) * 9 + rem;               // source input-dim
    float sspv = ssp[d * OD + n];
    ushort sb = f2bf(sbase[d * OD + n]);
    ushort v[8];
    #pragma unroll
    for (int f = 0; f < 6; ++f) v[f] = f2bf(coef[(d * OD + n) * 6 + f] * sspv);
    v[6] = sb; v[7] = sb;
    uint4 pk;
    pk.x = (unsigned)v[0] | ((unsigned)v[1] << 16);
    pk.y = (unsigned)v[2] | ((unsigned)v[3] << 16);
    pk.z = (unsigned)v[4] | ((unsigned)v[5] << 16);
    pk.w = (unsigned)v[6] | ((unsigned)v[7] << 16);
    *(uint4*)&wpb[(size_t)g * 8] = pk;
}

// ---- fused kernel: feature tile in LDS + barrier-free MFMA K-loop ----
__global__ __launch_bounds__(256) void kan_fused(const float* __restrict__ x,
                                                 const uint4* __restrict__ wpb,
                                                 float* __restrict__ out) {
    __shared__ uint4 feat[FEAT_U4];          // 65,792 B -> 2 blocks/CU

    const int tid  = threadIdx.x;
    const int wid  = tid >> 6;
    const int lane = tid & 63;
    const int l31  = lane & 31;
    const int hi   = lane >> 5;
    const int mt   = blockIdx.x;             // 0..30, h0 = 2*mt (rows h0..h0+3 <= 63)
    const int bb   = blockIdx.y;
    const int h0   = mt * 2;

    // ---- fill: 16c x 4r x 64w features into LDS (coalesced x, conflict-free writes)
    #pragma unroll
    for (int j = 0; j < 16; ++j) {
        int i = tid + j * 256;
        int c = i >> 8, r = (i >> 6) & 3, w = i & 63;
        float xv = x[(size_t)bb * 65536 + c * 4096 + (h0 + r) * 64 + w];
        feat[i] = feat_pack(xv);
    }
    __syncthreads();

    f32x16 acc0, acc1;
    #pragma unroll
    for (int i = 0; i < 16; ++i) { acc0[i] = 0.0f; acc1[i] = 0.0f; }

    const int m0 = wid * 32 + l31;           // pixel row 0..127
    const int hh = m0 >> 6, w = m0 & 63;
    // A lane base (16B units): hi*256 + hh*64 + w  (c=2a+hi folded: +512a const)
    const short8* abase = (const short8*)feat + (hi * 256 + hh * 64 + w);
    // B lane base (16B units): hi*64 + n
    const uint4* bbase = wpb + hi * 64 + l31;

    short8 bfr[2][8];
    #pragma unroll
    for (int kk = 0; kk < 4; ++kk) {
        bfr[0][kk * 2 + 0] = *(const short8*)(bbase + (kk * 2) * 64);
        bfr[0][kk * 2 + 1] = *(const short8*)(bbase + (kk * 2) * 64 + 32);
    }

    #pragma unroll
    for (int kc = 0; kc < KC; ++kc) {
        const int cur = kc & 1;
        if (kc + 1 < KC) {
            #pragma unroll
            for (int kk = 0; kk < 4; ++kk) {
                bfr[cur ^ 1][kk * 2 + 0] = *(const short8*)(bbase + ((kc + 1) * 8 + kk * 2) * 64);
                bfr[cur ^ 1][kk * 2 + 1] = *(const short8*)(bbase + ((kc + 1) * 8 + kk * 2) * 64 + 32);
            }
        }
        #pragma unroll
        for (int kk = 0; kk < 4; ++kk) {
            const int p = kc * 4 + kk;       // compile-time
            const int a = p / 9, rem = p - a * 9, di = rem / 3, dj = rem - di * 3;
            short8 av = abase[512 * a + 64 * di + dj];     // ds offset immediate
            acc0 = __builtin_amdgcn_mfma_f32_32x32x16_bf16(av, bfr[cur][kk * 2 + 0], acc0, 0, 0, 0);
            acc1 = __builtin_amdgcn_mfma_f32_32x32x16_bf16(av, bfr[cur][kk * 2 + 1], acc1, 0, 0, 0);
        }
    }

    // ---- epilogue (validated in R6): C scratch [o=64][m stride 130], row stores
    __syncthreads();
    float* Csc = (float*)feat;
    #pragma unroll
    for (int r = 0; r < 16; ++r) {
        int ml = (r & 3) + ((r >> 2) << 3) + (hi << 2);
        Csc[(size_t)l31 * 130 + wid * 32 + ml]        = acc0[r];
        Csc[(size_t)(32 + l31) * 130 + wid * 32 + ml] = acc1[r];
    }
    __syncthreads();
    #pragma unroll
    for (int it = 0; it < 16; ++it) {
        int flat = it * 256 + tid;
        int o = flat >> 6, hh2 = (flat >> 5) & 1, fc = flat & 31;
        if (fc < 31) {
            float2 v = *(float2*)&Csc[(size_t)o * 130 + hh2 * 64 + fc * 2];
            *(float2*)&out[((size_t)(bb * OD + o) * HO + h0 + hh2) * WO + fc * 2] = v;
        }
    }
}

// =================== fallback path (small ws): round-2 kernels ===================
#define NCHUNK 36
#define FW 68
__global__ __launch_bounds__(256) void kan_prep(const float* __restrict__ coef,
                                                const float* __restrict__ sbase,
                                                const float* __restrict__ ssp,
                                                ushort* __restrict__ wp) {
    int idx = blockIdx.x * 256 + threadIdx.x;
    if (idx >= ND * OD * 8) return;
    int n = idx & 7, o = (idx >> 3) & 63, d = idx >> 9;
    float v = (n < 6) ? coef[(d * OD + o) * 6 + n] * ssp[d * OD + o] : sbase[d * OD + o];
    wp[idx] = f2bf(v);
}

__global__ __launch_bounds__(128) void kan_mfma(const float* __restrict__ x,
                                                const ushort* __restrict__ wp,
                                                float* __restrict__ out) {
    __shared__ uint4 feat[Cc * 4 * FW];
    const int rp = blockIdx.x, b = blockIdx.y, tid = threadIdx.x;
    const int wid = tid >> 6, lane = tid & 63, l15 = lane & 15, ks = lane >> 4;
    const int hrow0 = rp * 2;
    for (int i = tid; i < Cc * 4 * FW; i += 128) {
        int wl = i % FW, cr = i / FW, r = cr & 3, c = cr >> 2;
        int col = wl < Ww ? wl : Ww - 1;
        feat[i] = feat_pack(x[((b * Cc + c) * Hh + hrow0 + r) * Ww + col]);
    }
    __syncthreads();
    f32x4 acc[4][4];
    #pragma unroll
    for (int rt = 0; rt < 4; ++rt)
        #pragma unroll
        for (int ct = 0; ct < 4; ++ct) acc[rt][ct] = (f32x4){0.f, 0.f, 0.f, 0.f};
    auto loadA = [&](int chunk, short8* A) {
        int d = chunk * 4 + ks;
        int c = (d * 57) >> 9;
        int rem = d - c * 9;
        int di = (rem * 11) >> 5;
        int dj = rem - di * 3;
        const short8* ap = (const short8*)&feat[(c * 4 + wid + di) * FW + l15 + dj];
        A[0] = ap[0]; A[1] = ap[16]; A[2] = ap[32]; A[3] = ap[48];
    };
    auto loadB = [&](int chunk, short8* Bf) {
        int d = chunk * 4 + ks;
        const short8* bp = (const short8*)wp + (d * 64 + l15);
        Bf[0] = bp[0]; Bf[1] = bp[16]; Bf[2] = bp[32]; Bf[3] = bp[48];
    };
    short8 A0[4], B0[4], A1[4], B1[4];
    loadA(0, A0); loadB(0, B0);
    for (int cb = 0; cb < NCHUNK; cb += 2) {
        loadA(cb + 1, A1); loadB(cb + 1, B1);
        #pragma unroll
        for (int rt = 0; rt < 4; ++rt)
            #pragma unroll
            for (int ct = 0; ct < 4; ++ct)
                acc[rt][ct] = __builtin_amdgcn_mfma_f32_16x16x32_bf16(A0[rt], B0[ct], acc[rt][ct], 0, 0, 0);
        if (cb + 2 < NCHUNK) { loadA(cb + 2, A0); loadB(cb + 2, B0); }
        #pragma unroll
        for (int rt = 0; rt < 4; ++rt)
            #pragma unroll
            for (int ct = 0; ct < 4; ++ct)
                acc[rt][ct] = __builtin_amdgcn_mfma_f32_16x16x32_bf16(A1[rt], B1[ct], acc[rt][ct], 0, 0, 0);
    }
    __syncthreads();
    float* sC = ((float*)feat) + wid * (OD * FW);
    #pragma unroll
    for (int rt = 0; rt < 4; ++rt)
        #pragma unroll
        for (int ct = 0; ct < 4; ++ct)
            *(f32x4*)&sC[(ct * 16 + l15) * FW + rt * 16 + ks * 4] = acc[rt][ct];
    const int orow = hrow0 + wid;
    for (int j = 0; j < OD; ++j) {
        float v = sC[j * FW + lane];
        if (lane < WO) out[((b * OD + j) * HO + orow) * WO + lane] = v;
    }
}

extern "C" void kernel_launch(void* const* d_in, const int* in_sizes, int n_in,
                              void* d_out, int out_size, void* d_ws, size_t ws_size,
                              hipStream_t stream) {
    (void)in_sizes; (void)n_in; (void)out_size;
    const float* x     = (const float*)d_in[0];
    const float* coef  = (const float*)d_in[1];
    const float* sbase = (const float*)d_in[2];
    const float* ssp   = (const float*)d_in[3];
    float* out = (float*)d_out;

    const size_t wpb_bytes = (size_t)KC * 8 * 64 * 16;   // 147,456

    if (ws_size >= wpb_bytes + 4096) {
        uint4* wpb = (uint4*)d_ws;
        kan_prep4<<<36, 256, 0, stream>>>(coef, sbase, ssp, (ushort*)wpb);
        dim3 grid(31, Bsz);
        kan_fused<<<grid, 256, 0, stream>>>(x, wpb, out);
    } else if (ws_size >= (size_t)ND * OD * 8 * 2) {
        ushort* wp = (ushort*)d_ws;
        kan_prep<<<(ND * OD * 8 + 255) / 256, 256, 0, stream>>>(coef, sbase, ssp, wp);
        dim3 grid(HO / 2, Bsz);
        kan_mfma<<<grid, 128, 0, stream>>>(x, wp, out);
    }
}

// Round 8
// 49.053 us; speedup vs baseline: 1.4352x; 1.4352x over previous
//
#include <hip/hip_runtime.h>
#include <math.h>

#define Bsz 32
#define Cc  16
#define Hh  64
#define Ww  64
#define HO  62
#define WO  62
#define OD  64
#define ND  144
#define TILE_U4 (2048 + 16)   // 8c x 4r x 64w uint4 + overreach pad = 33,024 B

using short8 = __attribute__((ext_vector_type(8))) short;
using f32x4  = __attribute__((ext_vector_type(4))) float;
using f32x16 = __attribute__((ext_vector_type(16))) float;
typedef unsigned int u32;
typedef unsigned short ushort;

__device__ __forceinline__ ushort f2bf(float f) {
    union { float f; unsigned u; } v; v.f = f;
    unsigned r = v.u + 0x7fff + ((v.u >> 16) & 1);
    return (ushort)(r >> 16);
}
__device__ __forceinline__ float bf2f(ushort h) {
    union { unsigned u; float f; } v; v.u = ((unsigned)h) << 16; return v.f;
}

__device__ __forceinline__ uint4 feat_pack(float xv) {
    float xi = (xv + 3.0f) * 1.5f;
    float fi = floorf(xi);
    int   ii = (int)fi;
    float u  = xi - fi;
    float u2 = u * u, u3 = u2 * u;
    float P0 = u3 * (1.0f / 6.0f);
    float P1 = (1.0f + 3.0f * u + 3.0f * u2 - 3.0f * u3) * (1.0f / 6.0f);
    float P2 = (4.0f - 6.0f * u2 + 3.0f * u3) * (1.0f / 6.0f);
    float om = 1.0f - u;
    float P3 = om * om * om * (1.0f / 6.0f);
    bool ok = (ii >= 0) && (ii <= 8);
    float bas[6];
    #pragma unroll
    for (int n = 0; n < 6; ++n) {
        int t = ii - n;
        float v = (t == 0) ? P0 : (t == 1) ? P1 : (t == 2) ? P2 : (t == 3) ? P3 : 0.0f;
        bas[n] = ok ? v : 0.0f;
    }
    float s = xv / (1.0f + __expf(-xv));
    ushort sh = f2bf(s);
    ushort sl = f2bf(s - bf2f(sh));
    uint4 pk;
    pk.x = (unsigned)f2bf(bas[0]) | ((unsigned)f2bf(bas[1]) << 16);
    pk.y = (unsigned)f2bf(bas[2]) | ((unsigned)f2bf(bas[3]) << 16);
    pk.z = (unsigned)f2bf(bas[4]) | ((unsigned)f2bf(bas[5]) << 16);
    pk.w = (unsigned)sh | ((unsigned)sl << 16);
    return pk;
}

// ---- B image, pass-aware c-pair permutation:
//      slot = pass*72 + kcl*8 + 2*kk + par ; p = kcl*4+kk = a*9+rem ;
//      d = (pass*8 + 2*a + par)*9 + rem ----
__global__ __launch_bounds__(256) void kan_prep5(const float* __restrict__ coef,
                                                 const float* __restrict__ sbase,
                                                 const float* __restrict__ ssp,
                                                 ushort* __restrict__ wpb) {
    int g = blockIdx.x * 256 + threadIdx.x;        // (slot, n)
    if (g >= ND * 64) return;
    int n = g & 63, slot = g >> 6;                 // slot 0..143
    int pass = slot / 72, r72 = slot - pass * 72;
    int kcl = r72 >> 3, sl = r72 & 7, kk = sl >> 1, par = sl & 1;
    int p = kcl * 4 + kk;                          // 0..35
    int a = p / 9, rem = p - a * 9;
    int c = pass * 8 + 2 * a + par;
    int d = c * 9 + rem;
    float sspv = ssp[d * OD + n];
    ushort sb = f2bf(sbase[d * OD + n]);
    ushort v[8];
    #pragma unroll
    for (int f = 0; f < 6; ++f) v[f] = f2bf(coef[(d * OD + n) * 6 + f] * sspv);
    v[6] = sb; v[7] = sb;
    uint4 pk;
    pk.x = (unsigned)v[0] | ((unsigned)v[1] << 16);
    pk.y = (unsigned)v[2] | ((unsigned)v[3] << 16);
    pk.z = (unsigned)v[4] | ((unsigned)v[5] << 16);
    pk.w = (unsigned)v[6] | ((unsigned)v[7] << 16);
    *(uint4*)&wpb[(size_t)g * 8] = pk;
}

// ---- fused kernel v2: half-tile (8c) in LDS, two passes, 4 blocks/CU,
//      no register arrays, B loaded fresh from L1 per step ----
__global__ __launch_bounds__(256, 4) void kan_fused2(const float* __restrict__ x,
                                                     const uint4* __restrict__ wpb,
                                                     float* __restrict__ out) {
    __shared__ uint4 feat[TILE_U4];          // 33,024 B -> 4 blocks/CU

    const int tid  = threadIdx.x;
    const int wid  = tid >> 6;
    const int lane = tid & 63;
    const int l31  = lane & 31;
    const int hi   = lane >> 5;
    const int mt   = blockIdx.x;             // 0..30, h0 = 2*mt
    const int bb   = blockIdx.y;
    const int h0   = mt * 2;

    f32x16 acc0, acc1;
    #pragma unroll
    for (int i = 0; i < 16; ++i) { acc0[i] = 0.0f; acc1[i] = 0.0f; }

    const int m0 = wid * 32 + l31;           // pixel row 0..127
    const int hh = m0 >> 6, w = m0 & 63;
    // A lane base (16B units): local c = 2a+hi -> unit (2a+hi)*256 + (di+hh)*64 + w+dj
    const short8* abase = (const short8*)feat + (hi * 256 + hh * 64 + w);
    // B lane base (16B units): slot-lane hi, col l31
    const uint4* bbase = wpb + hi * 64 + l31;

    const int fr = tid >> 6, fw = tid & 63;  // fill: row, col (per j: channel)

    #pragma unroll
    for (int pass = 0; pass < 2; ++pass) {
        if (pass) __syncthreads();           // protect tile from previous K-loop readers
        #pragma unroll
        for (int j = 0; j < 8; ++j) {
            float xv = x[(size_t)bb * 65536 + (pass * 8 + j) * 4096 + (h0 + fr) * 64 + fw];
            feat[j * 256 + tid] = feat_pack(xv);
        }
        __syncthreads();

        #pragma unroll
        for (int kcl = 0; kcl < 9; ++kcl) {
            #pragma unroll
            for (int kk = 0; kk < 4; ++kk) {
                const int p = kcl * 4 + kk;              // compile-time
                const int a = p / 9, rem = p - a * 9;
                const int di = rem / 3, dj = rem - di * 3;
                short8 av = abase[512 * a + 64 * di + dj];
                const uint4* bstep = bbase + (pass * 72 + kcl * 8 + kk * 2) * 64;
                short8 b0 = *(const short8*)(bstep);
                short8 b1 = *(const short8*)(bstep + 32);
                acc0 = __builtin_amdgcn_mfma_f32_32x32x16_bf16(av, b0, acc0, 0, 0, 0);
                acc1 = __builtin_amdgcn_mfma_f32_32x32x16_bf16(av, b1, acc1, 0, 0, 0);
            }
        }
    }

    // ---- epilogue, two phases through [32][130] f32 scratch (16,640 B) ----
    float* Csc = (float*)feat;
    __syncthreads();
    {   // phase 1: acc0 -> o = 0..31
        #pragma unroll
        for (int r = 0; r < 16; ++r) {
            int ml = (r & 3) + ((r >> 2) << 3) + (hi << 2);
            Csc[(size_t)l31 * 130 + wid * 32 + ml] = acc0[r];
        }
        __syncthreads();
        #pragma unroll
        for (int it = 0; it < 8; ++it) {
            int flat = it * 256 + tid;
            int o = flat >> 6, hh2 = (flat >> 5) & 1, fc = flat & 31;
            if (fc < 31) {
                float2 v = *(float2*)&Csc[(size_t)o * 130 + hh2 * 64 + fc * 2];
                *(float2*)&out[((size_t)(bb * OD + o) * HO + h0 + hh2) * WO + fc * 2] = v;
            }
        }
    }
    __syncthreads();
    {   // phase 2: acc1 -> o = 32..63
        #pragma unroll
        for (int r = 0; r < 16; ++r) {
            int ml = (r & 3) + ((r >> 2) << 3) + (hi << 2);
            Csc[(size_t)l31 * 130 + wid * 32 + ml] = acc1[r];
        }
        __syncthreads();
        #pragma unroll
        for (int it = 0; it < 8; ++it) {
            int flat = it * 256 + tid;
            int o = flat >> 6, hh2 = (flat >> 5) & 1, fc = flat & 31;
            if (fc < 31) {
                float2 v = *(float2*)&Csc[(size_t)o * 130 + hh2 * 64 + fc * 2];
                *(float2*)&out[((size_t)(bb * OD + 32 + o) * HO + h0 + hh2) * WO + fc * 2] = v;
            }
        }
    }
}

// =================== fallback path (small ws): round-2 kernels ===================
#define NCHUNK 36
#define FW 68
__global__ __launch_bounds__(256) void kan_prep(const float* __restrict__ coef,
                                                const float* __restrict__ sbase,
                                                const float* __restrict__ ssp,
                                                ushort* __restrict__ wp) {
    int idx = blockIdx.x * 256 + threadIdx.x;
    if (idx >= ND * OD * 8) return;
    int n = idx & 7, o = (idx >> 3) & 63, d = idx >> 9;
    float v = (n < 6) ? coef[(d * OD + o) * 6 + n] * ssp[d * OD + o] : sbase[d * OD + o];
    wp[idx] = f2bf(v);
}

__global__ __launch_bounds__(128) void kan_mfma(const float* __restrict__ x,
                                                const ushort* __restrict__ wp,
                                                float* __restrict__ out) {
    __shared__ uint4 feat[Cc * 4 * FW];
    const int rp = blockIdx.x, b = blockIdx.y, tid = threadIdx.x;
    const int wid = tid >> 6, lane = tid & 63, l15 = lane & 15, ks = lane >> 4;
    const int hrow0 = rp * 2;
    for (int i = tid; i < Cc * 4 * FW; i += 128) {
        int wl = i % FW, cr = i / FW, r = cr & 3, c = cr >> 2;
        int col = wl < Ww ? wl : Ww - 1;
        feat[i] = feat_pack(x[((b * Cc + c) * Hh + hrow0 + r) * Ww + col]);
    }
    __syncthreads();
    f32x4 acc[4][4];
    #pragma unroll
    for (int rt = 0; rt < 4; ++rt)
        #pragma unroll
        for (int ct = 0; ct < 4; ++ct) acc[rt][ct] = (f32x4){0.f, 0.f, 0.f, 0.f};
    auto loadA = [&](int chunk, short8* A) {
        int d = chunk * 4 + ks;
        int c = (d * 57) >> 9;
        int rem = d - c * 9;
        int di = (rem * 11) >> 5;
        int dj = rem - di * 3;
        const short8* ap = (const short8*)&feat[(c * 4 + wid + di) * FW + l15 + dj];
        A[0] = ap[0]; A[1] = ap[16]; A[2] = ap[32]; A[3] = ap[48];
    };
    auto loadB = [&](int chunk, short8* Bf) {
        int d = chunk * 4 + ks;
        const short8* bp = (const short8*)wp + (d * 64 + l15);
        Bf[0] = bp[0]; Bf[1] = bp[16]; Bf[2] = bp[32]; Bf[3] = bp[48];
    };
    short8 A0[4], B0[4], A1[4], B1[4];
    loadA(0, A0); loadB(0, B0);
    for (int cb = 0; cb < NCHUNK; cb += 2) {
        loadA(cb + 1, A1); loadB(cb + 1, B1);
        #pragma unroll
        for (int rt = 0; rt < 4; ++rt)
            #pragma unroll
            for (int ct = 0; ct < 4; ++ct)
                acc[rt][ct] = __builtin_amdgcn_mfma_f32_16x16x32_bf16(A0[rt], B0[ct], acc[rt][ct], 0, 0, 0);
        if (cb + 2 < NCHUNK) { loadA(cb + 2, A0); loadB(cb + 2, B0); }
        #pragma unroll
        for (int rt = 0; rt < 4; ++rt)
            #pragma unroll
            for (int ct = 0; ct < 4; ++ct)
                acc[rt][ct] = __builtin_amdgcn_mfma_f32_16x16x32_bf16(A1[rt], B1[ct], acc[rt][ct], 0, 0, 0);
    }
    __syncthreads();
    float* sC = ((float*)feat) + wid * (OD * FW);
    #pragma unroll
    for (int rt = 0; rt < 4; ++rt)
        #pragma unroll
        for (int ct = 0; ct < 4; ++ct)
            *(f32x4*)&sC[(ct * 16 + l15) * FW + rt * 16 + ks * 4] = acc[rt][ct];
    const int orow = hrow0 + wid;
    for (int j = 0; j < OD; ++j) {
        float v = sC[j * FW + lane];
        if (lane < WO) out[((b * OD + j) * HO + orow) * WO + lane] = v;
    }
}

extern "C" void kernel_launch(void* const* d_in, const int* in_sizes, int n_in,
                              void* d_out, int out_size, void* d_ws, size_t ws_size,
                              hipStream_t stream) {
    (void)in_sizes; (void)n_in; (void)out_size;
    const float* x     = (const float*)d_in[0];
    const float* coef  = (const float*)d_in[1];
    const float* sbase = (const float*)d_in[2];
    const float* ssp   = (const float*)d_in[3];
    float* out = (float*)d_out;

    const size_t wpb_bytes = (size_t)ND * 64 * 16;   // 147,456

    if (ws_size >= wpb_bytes + 4096) {
        uint4* wpb = (uint4*)d_ws;
        kan_prep5<<<36, 256, 0, stream>>>(coef, sbase, ssp, (ushort*)wpb);
        dim3 grid(31, Bsz);
        kan_fused2<<<grid, 256, 0, stream>>>(x, wpb, out);
    } else if (ws_size >= (size_t)ND * OD * 8 * 2) {
        ushort* wp = (ushort*)d_ws;
        kan_prep<<<(ND * OD * 8 + 255) / 256, 256, 0, stream>>>(coef, sbase, ssp, wp);
        dim3 grid(HO / 2, Bsz);
        kan_mfma<<<grid, 128, 0, stream>>>(x, wp, out);
    }
}